// Round 5
// baseline (313.232 us; speedup 1.0000x reference)
//
#include <hip/hip_runtime.h>

// TFF_Angle: angle force-field energy + force scatter.
// Inputs: 0 dist(N,N) f32 | 1 vec(N,N,3) f32 | 2 forces0(N,3) f32 |
//         3 params(A,2) f32 | 4 coord_idx(A,3) i32 | 5 calc_energy i32 | 6 calc_forces i32
// Output: [energy] ++ forces(N*3), fp32.
//
// R9 structure: 2 plain dispatches, fp32 partials, NB=128.
//   Session post-mortems baked in:
//     R3: cooperative fusion = +128us (coop launch serializes vs harness
//         fills/graph; 147us fully-exposed kernel). Never fuse via coop.
//     R2: halving gather lines via packed table = +-0 -> angle kernel is
//         latency-short, not gather-throughput-bound. No tables.
//     R4: bf16 partials = +3us vs fp32 (pack/unpack VALU ate the saving,
//         absmax 2->16). fp32 partials restored.
//   Window model: ~280us harness floor (2x119us poison fills + restores +
//   launch gaps) + our ~16us slice (angle ~10us latency-bound, reduce ~4us,
//   2 launch slots).
//   R9 change vs R1: NB 256->128 with 2 angles/thread (ILP-2 gathers).
//   Halves partial traffic (flush 12.6->6.3MB write, reduce 12.6->6.3MB
//   read) and halves reduction depth; same total gather concurrency.
//   1) angle_fused_kernel<true>: 128 blocks x 1024 thr; 2 angles/thread;
//      idx/param loads issued before LDS zero; all 4+4 gathers issued
//      before the barrier; per-block LDS fp32 accumulator (48 KB);
//      flush = coalesced float4 store to ws[b][nf] + energy partial.
//   2) reduce_kernel: out[1+j] = forces0[j] + sum_{b<128} ws[b][j]
//      (192 blocks x 256 thr, 4 groups x 32 partials); block 0 reduces
//      energy partials into out[0]. Zero global atomics.
//   Fallbacks (ws too small / too many angles): init_out + atomic path.

#define NB 128    // angle blocks; also = number of partials
#define NT 1024   // threads per angle block
#define ANG 2     // angles per thread (main path)

__global__ void init_out_kernel(float* __restrict__ out,
                                const float* __restrict__ forces0,
                                int nf) {
    int j = blockIdx.x * blockDim.x + threadIdx.x;
    if (j == 0) out[0] = 0.0f;
    if (j < nf) out[1 + j] = forces0[j];
}

__device__ __forceinline__ void angle_force(int ce, int cf,
                                            float v21x, float v21y, float v21z,
                                            float v23x, float v23y, float v23z,
                                            float d21, float d23, float2 kt,
                                            int a1, int a2, int a3,
                                            float* __restrict__ s_f,
                                            float& e_acc) {
    float c = v21x * v23x + v21y * v23y + v21z * v23z;
    c = fminf(1.0f, fmaxf(-1.0f, c));
    const float th  = acosf(c);
    const float dth = th - kt.y;

    if (ce) e_acc += kt.x * dth * dth;

    if (cf) {
        const float s2 = fmaxf(0.0f, 1.0f - c * c);
        const float s  = sqrtf(s2);
        const float coef = (s > 0.0f) ? (-2.0f * kt.x * dth / fmaxf(s, 1e-12f)) : 0.0f;
        const float i21 = coef / d21;
        const float i23 = coef / d23;

        const float f0x = i21 * (c * v21x - v23x);
        const float f0y = i21 * (c * v21y - v23y);
        const float f0z = i21 * (c * v21z - v23z);
        const float f2x = i23 * (c * v23x - v21x);
        const float f2y = i23 * (c * v23y - v21y);
        const float f2z = i23 * (c * v23z - v21z);

        atomicAdd(&s_f[a1 * 3 + 0], f0x);
        atomicAdd(&s_f[a1 * 3 + 1], f0y);
        atomicAdd(&s_f[a1 * 3 + 2], f0z);
        atomicAdd(&s_f[a2 * 3 + 0], -(f0x + f2x));
        atomicAdd(&s_f[a2 * 3 + 1], -(f0y + f2y));
        atomicAdd(&s_f[a2 * 3 + 2], -(f0z + f2z));
        atomicAdd(&s_f[a3 * 3 + 0], f2x);
        atomicAdd(&s_f[a3 * 3 + 1], f2y);
        atomicAdd(&s_f[a3 * 3 + 2], f2z);
    }
}

// USE_WS=1: ILP-2 main path, flush fp32 partials to ws_f + energy to ws_e.
// USE_WS=0: generic-loop fallback, zero-skipping global-atomic flush.
template <bool USE_WS>
__global__ void __launch_bounds__(NT)
angle_fused_kernel(const float*  __restrict__ dist,
                   const float*  __restrict__ vec,
                   const float2* __restrict__ params,
                   const int*    __restrict__ cidx,
                   const int*    __restrict__ ce_p,
                   const int*    __restrict__ cf_p,
                   float* __restrict__ out,    // fallback only
                   float* __restrict__ ws_f,   // [NB][nf] fp32 partials
                   float* __restrict__ ws_e,   // [NB] energy partials
                   int n_atoms, int n_angles) {
    extern __shared__ float s_f[];            // nf floats (48 KB at N=4096)
    __shared__ float s_e;
    const int nf  = n_atoms * 3;
    const int tid = threadIdx.x;
    const int b   = blockIdx.x;

    // even range split: every block gets ~n_angles/NB contiguous angles
    const int i0 = (int)(((long)b * n_angles) / NB);
    const int i1 = (int)(((long)(b + 1) * n_angles) / NB);

    const int ce = ce_p[0];
    const int cf = cf_p[0];
    float e_acc = 0.0f;

    if constexpr (USE_WS) {
        // ---- ILP-2 main path: count per block <= ANG*NT (host-guarded) ----
        int    a1[ANG], a2[ANG], a3[ANG];
        float2 kt[ANG];
        bool   act[ANG];

        // epoch 1: issue all index/param loads (latency hides under LDS zero)
        #pragma unroll
        for (int k = 0; k < ANG; ++k) {
            const int i = i0 + tid + k * NT;
            act[k] = (i < i1);
            a1[k] = 0; a2[k] = 0; a3[k] = 0;
            kt[k] = make_float2(0.0f, 0.0f);
            if (act[k]) {
                a1[k] = cidx[3 * i + 0];
                a2[k] = cidx[3 * i + 1];
                a3[k] = cidx[3 * i + 2];
                kt[k] = params[i];
            }
        }

        {   // zero LDS accumulator while epoch-1 loads are in flight
            float4* __restrict__ s4 = (float4*)s_f;
            const int nf4 = nf >> 2;
            for (int q = tid; q < nf4; q += NT) s4[q] = make_float4(0.f, 0.f, 0.f, 0.f);
            for (int j = (nf4 << 2) + tid; j < nf; j += NT) s_f[j] = 0.0f;
            if (tid == 0) s_e = 0.0f;
        }

        // epoch 2: issue all gathers before the barrier (ILP-2, 8 loads)
        float v21x[ANG], v21y[ANG], v21z[ANG], d21[ANG];
        float v23x[ANG], v23y[ANG], v23z[ANG], d23[ANG];
        #pragma unroll
        for (int k = 0; k < ANG; ++k) {
            v21x[k] = v21y[k] = v21z[k] = 0.f; d21[k] = 1.f;
            v23x[k] = v23y[k] = v23z[k] = 0.f; d23[k] = 1.f;
            if (act[k]) {
                const unsigned row = (unsigned)a2[k] * (unsigned)n_atoms;
                const unsigned b21 = row + (unsigned)a1[k];
                const unsigned b23 = row + (unsigned)a3[k];
                const float* __restrict__ p21 = vec + 3u * b21;
                const float* __restrict__ p23 = vec + 3u * b23;
                v21x[k] = p21[0]; v21y[k] = p21[1]; v21z[k] = p21[2];
                v23x[k] = p23[0]; v23y[k] = p23[1]; v23z[k] = p23[2];
                d21[k] = dist[b21];
                d23[k] = dist[b23];
            }
        }

        __syncthreads();   // LDS zero visible to all

        #pragma unroll
        for (int k = 0; k < ANG; ++k) {
            if (act[k])
                angle_force(ce, cf, v21x[k], v21y[k], v21z[k],
                            v23x[k], v23y[k], v23z[k], d21[k], d23[k],
                            kt[k], a1[k], a2[k], a3[k], s_f, e_acc);
        }
    } else {
        // ---- generic fallback: any angle count, one angle per iteration ----
        for (int j = tid; j < nf; j += NT) s_f[j] = 0.0f;
        if (tid == 0) s_e = 0.0f;
        __syncthreads();

        for (int i = i0 + tid; i < i1; i += NT) {
            const int a1 = cidx[3 * i + 0];
            const int a2 = cidx[3 * i + 1];
            const int a3 = cidx[3 * i + 2];
            const float2 kt = params[i];
            const unsigned row = (unsigned)a2 * (unsigned)n_atoms;
            const unsigned b21 = row + (unsigned)a1;
            const unsigned b23 = row + (unsigned)a3;
            const float* __restrict__ p21 = vec + 3u * b21;
            const float* __restrict__ p23 = vec + 3u * b23;
            angle_force(ce, cf, p21[0], p21[1], p21[2],
                        p23[0], p23[1], p23[2], dist[b21], dist[b23],
                        kt, a1, a2, a3, s_f, e_acc);
        }
    }

    // per-block energy: wave shuffle, then LDS atomic (wave leaders)
    for (int off = 32; off > 0; off >>= 1)
        e_acc += __shfl_down(e_acc, off, 64);
    if ((tid & 63) == 0) atomicAdd(&s_e, e_acc);
    __syncthreads();   // orders all force LDS-atomics + energy before flush

    if constexpr (USE_WS) {
        // Coalesced fp32 partial store: 48 KB float4 stream, no atomics.
        // (s_f is valid-zero when cf==0, so unconditional store is correct.)
        float* __restrict__ wp = ws_f + (size_t)b * nf;
        const float4* __restrict__ s4 = (const float4*)s_f;
        float4* __restrict__ w4 = (float4*)wp;
        const int nf4 = nf >> 2;
        for (int q = tid; q < nf4; q += NT) w4[q] = s4[q];
        for (int j = (nf4 << 2) + tid; j < nf; j += NT) wp[j] = s_f[j];
        if (tid == 0) ws_e[b] = s_e;   // 0 when !ce
    } else {
        if (ce && tid == 0) atomicAdd(&out[0], s_e);
        if (cf) {
            const int base = (b * (nf / NB)) % nf;
            for (int jj = tid; jj < nf; jj += NT) {
                int j = jj + base;
                if (j >= nf) j -= nf;
                const float v = s_f[j];
                if (v != 0.0f) atomicAdd(&out[1 + j], v);
            }
        }
    }
}

// Phase B: out[1+j] = forces0[j] + sum_{b<NB} ws[b][j]; block 0 reduces energy.
// 256 threads = 64 j-lanes x 4 partial-groups of 32; per-wave reads are
// 64 consecutive floats (256 B, coalesced), stride nf between iterations.
__global__ void __launch_bounds__(256)
reduce_kernel(const float* __restrict__ ws_f,   // [NB][nf]
              const float* __restrict__ ws_e,   // [NB]
              const float* __restrict__ forces0,
              const int*   __restrict__ ce_p,
              float* __restrict__ out,
              int nf) {
    const int t  = threadIdx.x;
    const int jj = t & 63;
    const int bg = t >> 6;                 // 0..3
    const int j  = blockIdx.x * 64 + jj;

    __shared__ float s_p[4][64];
    __shared__ float s_e;

    float acc = 0.0f;
    if (j < nf) {
        const float* __restrict__ p = ws_f + (size_t)(bg * (NB / 4)) * nf + j;
        #pragma unroll 8
        for (int b = 0; b < NB / 4; ++b) acc += p[(size_t)b * nf];
    }
    s_p[bg][jj] = acc;

    float e = (blockIdx.x == 0 && t < NB) ? ws_e[t] : 0.0f;
    if (t == 0) s_e = 0.0f;
    __syncthreads();

    if (blockIdx.x == 0) {
        for (int off = 32; off > 0; off >>= 1) e += __shfl_down(e, off, 64);
        if ((t & 63) == 0) atomicAdd(&s_e, e);
    }
    if (bg == 0 && j < nf)
        out[1 + j] = forces0[j] + s_p[0][jj] + s_p[1][jj] + s_p[2][jj] + s_p[3][jj];
    __syncthreads();
    if (blockIdx.x == 0 && t == 0) out[0] = ce_p[0] ? s_e : 0.0f;
}

extern "C" void kernel_launch(void* const* d_in, const int* in_sizes, int n_in,
                              void* d_out, int out_size, void* d_ws, size_t ws_size,
                              hipStream_t stream) {
    const float*  dist    = (const float*)d_in[0];
    const float*  vec     = (const float*)d_in[1];
    const float*  forces0 = (const float*)d_in[2];
    const float2* params  = (const float2*)d_in[3];
    const int*    cidx    = (const int*)d_in[4];
    const int*    ce_p    = (const int*)d_in[5];
    const int*    cf_p    = (const int*)d_in[6];
    float* out = (float*)d_out;

    const int n_atoms  = in_sizes[2] / 3;
    const int n_angles = in_sizes[4] / 3;
    const int nf = n_atoms * 3;

    const size_t lds_bytes = (size_t)nf * sizeof(float);               // 48 KB
    const size_t ws_need   = ((size_t)NB * nf + NB) * sizeof(float);   // ~6.3 MiB

    const bool main_ok = (d_ws != nullptr) && (ws_size >= ws_need) &&
                         (n_angles <= NB * NT * ANG) &&
                         (lds_bytes <= 160 * 1024 - 1024);

    if (main_ok) {
        float* ws_f = (float*)d_ws;
        float* ws_e = ws_f + (size_t)NB * nf;
        angle_fused_kernel<true><<<NB, NT, lds_bytes, stream>>>(
            dist, vec, params, cidx, ce_p, cf_p, out, ws_f, ws_e,
            n_atoms, n_angles);
        const int rblocks = (nf + 63) / 64;   // 192 at N=4096
        reduce_kernel<<<rblocks, 256, 0, stream>>>(ws_f, ws_e, forces0,
                                                   ce_p, out, nf);
    } else {
        // Fallback: init + zero-skipping atomic flush (proven path)
        init_out_kernel<<<(nf + 1 + 255) / 256, 256, 0, stream>>>(out, forces0, nf);
        angle_fused_kernel<false><<<NB, NT, lds_bytes, stream>>>(
            dist, vec, params, cidx, ce_p, cf_p, out, nullptr, nullptr,
            n_atoms, n_angles);
    }
}

// Round 6
// 301.293 us; speedup vs baseline: 1.0396x; 1.0396x over previous
//
#include <hip/hip_runtime.h>

// TFF_Angle: angle force-field energy + force scatter.
// Inputs: 0 dist(N,N) f32 | 1 vec(N,N,3) f32 | 2 forces0(N,3) f32 |
//         3 params(A,2) f32 | 4 coord_idx(A,3) i32 | 5 calc_energy i32 | 6 calc_forces i32
// Output: [energy] ++ forces(N*3), fp32.
//
// R10 = R1 restored: the measured optimum of this session.
//   Ledger: R0 atomic-flush 301.5 | R1 store+reduce 296.5 | R2 +packed
//   table 295.4 (noise, +1 dispatch) | R3 coop fusion 423.6 | R4 bf16
//   partials 299.8 | R5 NB=128/ILP2 313.2.
//   Window model: ~280us harness floor (2x~120us poison fills at 83-85%
//   HBM peak + restore dispatches + launch gaps) + our ~16us slice
//   (angle ~10us gather-LATENCY-bound across 256 CUs — line-count halving
//   was worthless (R2), block-halving cost 17us (R5); reduce ~4us;
//   2 launch slots = structural minimum; coop fusion banned by R3).
//   1) angle_fused_kernel<true>: 256 blocks x 1024 thr, angles range-split;
//      idx/param loads issued before LDS zero; gathers before the barrier;
//      per-block LDS fp32 accumulator (48 KB); flush = coalesced float4
//      store to ws[b][nf] + fp32 energy partial. Zero global atomics.
//   2) reduce_kernel: out[1+j] = forces0[j] + sum_b ws[b][j] (192 blocks);
//      block 0 reduces the 256 energy partials into out[0].
//   Fallbacks (ws too small / too many angles): init_out + atomic path.

#define NB 256    // angle blocks (one per CU); also = number of partials
#define NT 1024   // threads per angle block

__global__ void init_out_kernel(float* __restrict__ out,
                                const float* __restrict__ forces0,
                                int nf) {
    int j = blockIdx.x * blockDim.x + threadIdx.x;
    if (j == 0) out[0] = 0.0f;
    if (j < nf) out[1 + j] = forces0[j];
}

template <bool USE_WS>
__global__ void __launch_bounds__(NT)
angle_fused_kernel(const float*  __restrict__ dist,
                   const float*  __restrict__ vec,
                   const float2* __restrict__ params,
                   const int*    __restrict__ cidx,
                   const int*    __restrict__ ce_p,
                   const int*    __restrict__ cf_p,
                   float* __restrict__ out,    // fallback only
                   float* __restrict__ ws_f,   // [NB][nf] fp32 partials
                   float* __restrict__ ws_e,   // [NB] energy partials
                   int n_atoms, int n_angles) {
    extern __shared__ float s_f[];            // nf floats (48 KB at N=4096)
    __shared__ float s_e;
    const int nf  = n_atoms * 3;
    const int tid = threadIdx.x;
    const int b   = blockIdx.x;

    // even range split: every block gets ~n_angles/NB contiguous angles
    const int i0 = (int)(((long)b * n_angles) / NB);
    const int i1 = (int)(((long)(b + 1) * n_angles) / NB);
    const int i  = i0 + tid;
    const bool active = (i < i1);

    // epoch 1: issue index/param loads first (latency hides under LDS zero)
    int a1 = 0, a2 = 0, a3 = 0;
    float2 kt = make_float2(0.0f, 0.0f);
    if (active) {
        a1 = cidx[3 * i + 0];
        a2 = cidx[3 * i + 1];
        a3 = cidx[3 * i + 2];
        kt = params[i];
    }

    {   // zero LDS accumulator while epoch-1 loads are in flight
        float4* __restrict__ s4 = (float4*)s_f;
        const int nf4 = nf >> 2;
        for (int q = tid; q < nf4; q += NT) s4[q] = make_float4(0.f, 0.f, 0.f, 0.f);
        for (int j = (nf4 << 2) + tid; j < nf; j += NT) s_f[j] = 0.0f;
        if (tid == 0) s_e = 0.0f;
    }

    const int ce = ce_p[0];
    const int cf = cf_p[0];

    // epoch 2: issue gathers before the barrier (barrier doesn't drain vmcnt)
    float v21x = 0.f, v21y = 0.f, v21z = 0.f, d21 = 1.f;
    float v23x = 0.f, v23y = 0.f, v23z = 0.f, d23 = 1.f;
    if (active) {
        const unsigned row = (unsigned)a2 * (unsigned)n_atoms;
        const unsigned b21 = row + (unsigned)a1;
        const unsigned b23 = row + (unsigned)a3;
        const float* __restrict__ p21 = vec + 3u * b21;
        const float* __restrict__ p23 = vec + 3u * b23;
        v21x = p21[0]; v21y = p21[1]; v21z = p21[2];
        v23x = p23[0]; v23y = p23[1]; v23z = p23[2];
        d21 = dist[b21];
        d23 = dist[b23];
    }

    __syncthreads();   // LDS zero visible to all

    float e_acc = 0.0f;
    if (active) {
        float c = v21x * v23x + v21y * v23y + v21z * v23z;
        c = fminf(1.0f, fmaxf(-1.0f, c));
        const float th  = acosf(c);
        const float dth = th - kt.y;

        if (ce) e_acc = kt.x * dth * dth;

        if (cf) {
            const float s2 = fmaxf(0.0f, 1.0f - c * c);
            const float s  = sqrtf(s2);
            const float coef = (s > 0.0f) ? (-2.0f * kt.x * dth / fmaxf(s, 1e-12f)) : 0.0f;
            const float i21 = coef / d21;
            const float i23 = coef / d23;

            const float f0x = i21 * (c * v21x - v23x);
            const float f0y = i21 * (c * v21y - v23y);
            const float f0z = i21 * (c * v21z - v23z);
            const float f2x = i23 * (c * v23x - v21x);
            const float f2y = i23 * (c * v23y - v21y);
            const float f2z = i23 * (c * v23z - v21z);

            atomicAdd(&s_f[a1 * 3 + 0], f0x);
            atomicAdd(&s_f[a1 * 3 + 1], f0y);
            atomicAdd(&s_f[a1 * 3 + 2], f0z);
            atomicAdd(&s_f[a2 * 3 + 0], -(f0x + f2x));
            atomicAdd(&s_f[a2 * 3 + 1], -(f0y + f2y));
            atomicAdd(&s_f[a2 * 3 + 2], -(f0z + f2z));
            atomicAdd(&s_f[a3 * 3 + 0], f2x);
            atomicAdd(&s_f[a3 * 3 + 1], f2y);
            atomicAdd(&s_f[a3 * 3 + 2], f2z);
        }
    }

    // per-block energy: wave shuffle, then LDS atomic (16 wave leaders)
    for (int off = 32; off > 0; off >>= 1)
        e_acc += __shfl_down(e_acc, off, 64);
    if ((tid & 63) == 0) atomicAdd(&s_e, e_acc);
    __syncthreads();   // orders all force LDS-atomics + energy before flush

    if constexpr (USE_WS) {
        // Coalesced partial store: 48 KB float4 stream, no atomics.
        // (s_f is valid-zero when cf==0, so unconditional store is correct.)
        float* __restrict__ wp = ws_f + (size_t)b * nf;
        const float4* __restrict__ s4 = (const float4*)s_f;
        float4* __restrict__ w4 = (float4*)wp;
        const int nf4 = nf >> 2;
        for (int q = tid; q < nf4; q += NT) w4[q] = s4[q];
        for (int j = (nf4 << 2) + tid; j < nf; j += NT) wp[j] = s_f[j];
        if (tid == 0) ws_e[b] = s_e;   // 0 when !ce
    } else {
        if (ce && tid == 0) atomicAdd(&out[0], s_e);
        if (cf) {
            // staggered zero-skipping atomic flush (fallback path)
            const int base = (b * (nf / NB)) % nf;
            for (int jj = tid; jj < nf; jj += NT) {
                int j = jj + base;
                if (j >= nf) j -= nf;
                const float v = s_f[j];
                if (v != 0.0f) atomicAdd(&out[1 + j], v);
            }
        }
    }
}

// Phase B: out[1+j] = forces0[j] + sum_b ws[b][j]; block 0 reduces energy.
// 256 threads = 64 j-lanes x 4 b-groups of 64 partials each; per-wave reads
// are 64 consecutive floats (256 B, coalesced), stride nf between iterations.
__global__ void __launch_bounds__(256)
reduce_kernel(const float* __restrict__ ws_f,   // [NB][nf]
              const float* __restrict__ ws_e,   // [NB]
              const float* __restrict__ forces0,
              const int*   __restrict__ ce_p,
              float* __restrict__ out,
              int nf) {
    const int t  = threadIdx.x;
    const int jj = t & 63;
    const int bg = t >> 6;                 // 0..3
    const int j  = blockIdx.x * 64 + jj;

    __shared__ float s_p[4][64];
    __shared__ float s_e;

    float acc = 0.0f;
    if (j < nf) {
        const float* __restrict__ p = ws_f + (size_t)(bg * 64) * nf + j;
        #pragma unroll 16
        for (int b = 0; b < 64; ++b) acc += p[(size_t)b * nf];
    }
    s_p[bg][jj] = acc;

    float e = (blockIdx.x == 0) ? ws_e[t] : 0.0f;   // NB == 256 == blockDim
    if (t == 0) s_e = 0.0f;
    __syncthreads();

    if (blockIdx.x == 0) {
        for (int off = 32; off > 0; off >>= 1) e += __shfl_down(e, off, 64);
        if ((t & 63) == 0) atomicAdd(&s_e, e);
    }
    if (bg == 0 && j < nf)
        out[1 + j] = forces0[j] + s_p[0][jj] + s_p[1][jj] + s_p[2][jj] + s_p[3][jj];
    __syncthreads();
    if (blockIdx.x == 0 && t == 0) out[0] = ce_p[0] ? s_e : 0.0f;
}

extern "C" void kernel_launch(void* const* d_in, const int* in_sizes, int n_in,
                              void* d_out, int out_size, void* d_ws, size_t ws_size,
                              hipStream_t stream) {
    const float*  dist    = (const float*)d_in[0];
    const float*  vec     = (const float*)d_in[1];
    const float*  forces0 = (const float*)d_in[2];
    const float2* params  = (const float2*)d_in[3];
    const int*    cidx    = (const int*)d_in[4];
    const int*    ce_p    = (const int*)d_in[5];
    const int*    cf_p    = (const int*)d_in[6];
    float* out = (float*)d_out;

    const int n_atoms  = in_sizes[2] / 3;
    const int n_angles = in_sizes[4] / 3;
    const int nf = n_atoms * 3;

    const size_t lds_bytes = (size_t)nf * sizeof(float);               // 48 KB
    const size_t ws_need   = ((size_t)NB * nf + NB) * sizeof(float);   // ~12.6 MiB

    const bool main_ok = (d_ws != nullptr) && (ws_size >= ws_need) &&
                         (n_angles <= NB * NT) &&
                         (lds_bytes <= 160 * 1024 - 1024);

    if (main_ok) {
        float* ws_f = (float*)d_ws;
        float* ws_e = ws_f + (size_t)NB * nf;
        angle_fused_kernel<true><<<NB, NT, lds_bytes, stream>>>(
            dist, vec, params, cidx, ce_p, cf_p, out, ws_f, ws_e,
            n_atoms, n_angles);
        const int rblocks = (nf + 63) / 64;   // 192 at N=4096
        reduce_kernel<<<rblocks, 256, 0, stream>>>(ws_f, ws_e, forces0,
                                                   ce_p, out, nf);
    } else {
        // Fallback: init + zero-skipping atomic flush (proven path)
        init_out_kernel<<<(nf + 1 + 255) / 256, 256, 0, stream>>>(out, forces0, nf);
        angle_fused_kernel<false><<<NB, NT, lds_bytes, stream>>>(
            dist, vec, params, cidx, ce_p, cf_p, out, nullptr, nullptr,
            n_atoms, n_angles);
    }
}